// Round 4
// baseline (1323.793 us; speedup 1.0000x reference)
//
#include <hip/hip_runtime.h>
#include <hip/hip_bf16.h>
#include <math.h>

#define NDIM 300
#define KPAD 320          // K padded: 300 x-dims + 3 normal dims + zeros
#define NREAL 1800
#define NPAD 1920         // 15 tiles of 128

typedef __hip_bfloat16 bf16;
typedef __attribute__((ext_vector_type(8))) short short8;   // 8 bf16 (4 VGPRs)
typedef __attribute__((ext_vector_type(4))) float f32x4;

__device__ __forceinline__ void gl_lds16(const void* g, void* l) {
    __builtin_amdgcn_global_load_lds(
        (const __attribute__((address_space(1))) void*)g,
        (__attribute__((address_space(3))) void*)l, 16, 0, 0);
}

// ---------------- tiny constant-folding kernels ----------------
__global__ void small_pre(
    const float* __restrict__ Wn, const float* __restrict__ bn,
    const float* __restrict__ Wxy, const float* __restrict__ bxy,
    const float* __restrict__ Wloc, const float* __restrict__ bloc,
    const float* __restrict__ bobj,
    const float* __restrict__ Wfus,
    const float* __restrict__ vocab,
    float* __restrict__ Wn1, float* __restrict__ Wn2,
    float* __restrict__ Mxy, float* __restrict__ bgeo,
    float* __restrict__ vf5, float* __restrict__ t0, float* __restrict__ t1)
{
    int i = blockIdx.x * blockDim.x + threadIdx.x;
    if (i < 900) {
        int r = i / 300, c = i % 300;
        float s = 0.f;
        for (int k = 0; k < 300; k++) s += Wn[r*300+k] * Wloc[(300+k)*300+c];
        Wn1[i] = s;
    } else if (i < 1800) {
        int j = i - 900; int r = j/300, c = j%300;
        float s = 0.f;
        for (int k = 0; k < 300; k++) s += Wn[r*300+k] * Wloc[(600+k)*300+c];
        Wn2[j] = s;
    } else if (i < 2400) {
        int j = i - 1800; int r = j/300, c = j%300;
        float s = 0.f;
        for (int k = 0; k < 300; k++) s += Wxy[r*300+k] * Wloc[k*300+c];
        Mxy[j] = s;
    } else if (i < 2700) {
        int c = i - 2400;
        float s = bloc[c] + bobj[c];
        for (int k = 0; k < 300; k++) s += bxy[k] * Wloc[k*300+c];
        for (int k = 0; k < 300; k++) s += bn[k] * (Wloc[(300+k)*300+c] + Wloc[(600+k)*300+c]);
        bgeo[c] = s;
    } else if (i < 4200) {
        int j = i - 2700; int p = j/300, c = j%300;
        float s = 0.f;
        for (int k = 0; k < 300; k++) s += vocab[(2+p)*300+k] * Wfus[(300+k)*300+c];
        vf5[j] = s;
    } else if (i < 4500) {
        int c = i - 4200;
        float s = 0.f;
        for (int k = 0; k < 300; k++) s += vocab[k] * Wfus[k*300+c];
        t0[c] = s;
    } else if (i < 4800) {
        int c = i - 4500;
        float s = 0.f;
        for (int k = 0; k < 300; k++) s += vocab[300+k] * Wfus[k*300+c];
        t1[c] = s;
    }
}

__global__ void small_pre2(
    const float* __restrict__ We, const float* __restrict__ bfus,
    const float* __restrict__ vf5, const float* __restrict__ t0, const float* __restrict__ t1,
    float* __restrict__ E8)
{
    int i = blockIdx.x * blockDim.x + threadIdx.x;
    if (i >= 2400) return;
    int r = i / 300, c = i % 300;
    const float* src;
    if (r == 0) src = t0;
    else if (r == 1) src = t1;
    else if (r == 7) src = bfus;
    else src = vf5 + (r - 2) * 300;
    float s = 0.f;
    for (int k = 0; k < 300; k++) s += src[k] * We[k*300+c];
    E8[i] = s;
}

// pack weights into WcatT[NPAD][KPAD] bf16 (transposed, K contiguous) + bcat fp32
__global__ void pack_w(
    const float* __restrict__ Wq, const float* __restrict__ Wk,
    const float* __restrict__ Wv, const float* __restrict__ Wskip,
    const float* __restrict__ Wobj,
    const float* __restrict__ Wn1, const float* __restrict__ Wn2,
    const float* __restrict__ bq, const float* __restrict__ bk,
    const float* __restrict__ bv, const float* __restrict__ bskip,
    bf16* __restrict__ WcatT, float* __restrict__ bcat)
{
    int i = blockIdx.x * blockDim.x + threadIdx.x;
    if (i < NREAL) {
        int seg = i / 300, jj = i % 300;
        float b = 0.f;
        if (seg == 0) b = bq[jj]; else if (seg == 1) b = bk[jj];
        else if (seg == 2) b = bv[jj]; else if (seg == 3) b = bskip[jj];
        bcat[i] = b;
    }
    if (i < NPAD * KPAD) {
        int c = i / KPAD, k = i % KPAD;
        float v = 0.f;
        if (c < NREAL) {
            int seg = c / 300, jj = c % 300;
            if (k < 300) {
                switch (seg) {
                    case 0: v = Wq[k*300+jj]; break;
                    case 1: v = Wk[k*300+jj]; break;
                    case 2: v = Wv[k*300+jj]; break;
                    case 3: v = Wskip[k*300+jj]; break;
                    case 4: v = Wobj[k*300+jj] - Wobj[(300+k)*300+jj]; break;
                    default: v = Wobj[(300+k)*300+jj]; break;
                }
            } else if (k < 303) {
                if (seg == 4) v = Wn1[(k-300)*300+jj];
                else if (seg == 5) v = Wn2[(k-300)*300+jj];
            }
        }
        WcatT[i] = __float2bfloat16(v);
    }
}

// ---------------- MFMA node-GEMM: [N,320]bf16 @ [320,1920]bf16 ----------------
__global__ __launch_bounds__(256) void gemm_mfma(
    const float* __restrict__ X, const float* __restrict__ Nrm,
    const bf16* __restrict__ Bt, const float* __restrict__ bcat,
    bf16* __restrict__ Q, bf16* __restrict__ Kf, bf16* __restrict__ V,
    float* __restrict__ Ot, bf16* __restrict__ Pi, bf16* __restrict__ Pj,
    int M)
{
    __shared__ __align__(16) bf16 As[128 * 32];
    __shared__ __align__(16) bf16 Bs[128 * 32];

    const int tid  = threadIdx.x;
    const int wave = tid >> 6;
    const int lane = tid & 63;
    const int r0 = blockIdx.y * 128;
    const int c0 = blockIdx.x * 128;
    const int wm = (wave >> 1) * 64;
    const int wn = (wave & 1) * 64;
    const int lr = lane & 15;
    const int lq = lane >> 4;

    f32x4 acc[4][4];
    #pragma unroll
    for (int i = 0; i < 4; i++)
        #pragma unroll
        for (int j = 0; j < 4; j++) acc[i][j] = (f32x4){0.f, 0.f, 0.f, 0.f};

    const int arow_l = tid >> 1;
    const int akp    = (tid & 1) * 16;
    const int agrow  = min(r0 + arow_l, M - 1);
    const float* xr = X + (size_t)agrow * 300;
    const float* nr = Nrm + (size_t)agrow * 3;
    const int bcol_l = lane >> 2;
    const int bkp    = (lane & 3) * 8;

    for (int kb = 0; kb < KPAD; kb += 32) {
        {
            int g = kb + akp;
            union { bf16 h[16]; short8 s[2]; } u;
            if (g + 16 <= 300) {
                const float4 f0 = *(const float4*)(xr + g);
                const float4 f1 = *(const float4*)(xr + g + 4);
                const float4 f2 = *(const float4*)(xr + g + 8);
                const float4 f3 = *(const float4*)(xr + g + 12);
                u.h[0]=__float2bfloat16(f0.x); u.h[1]=__float2bfloat16(f0.y);
                u.h[2]=__float2bfloat16(f0.z); u.h[3]=__float2bfloat16(f0.w);
                u.h[4]=__float2bfloat16(f1.x); u.h[5]=__float2bfloat16(f1.y);
                u.h[6]=__float2bfloat16(f1.z); u.h[7]=__float2bfloat16(f1.w);
                u.h[8]=__float2bfloat16(f2.x); u.h[9]=__float2bfloat16(f2.y);
                u.h[10]=__float2bfloat16(f2.z); u.h[11]=__float2bfloat16(f2.w);
                u.h[12]=__float2bfloat16(f3.x); u.h[13]=__float2bfloat16(f3.y);
                u.h[14]=__float2bfloat16(f3.z); u.h[15]=__float2bfloat16(f3.w);
            } else {
                #pragma unroll
                for (int t = 0; t < 16; t++) {
                    int gg = g + t;
                    float v = 0.f;
                    if (gg < 300)      v = xr[gg];
                    else if (gg < 303) v = nr[gg - 300];
                    u.h[t] = __float2bfloat16(v);
                }
            }
            *(short8*)&As[arow_l * 32 + akp]     = u.s[0];
            *(short8*)&As[arow_l * 32 + akp + 8] = u.s[1];
        }
        #pragma unroll
        for (int h = 0; h < 2; h++) {
            int cloc = wave * 32 + h * 16;
            const bf16* g = Bt + (size_t)(c0 + cloc + bcol_l) * KPAD + kb + bkp;
            gl_lds16(g, &Bs[cloc * 32]);
        }
        __syncthreads();
        short8 af[4], bfr[4];
        #pragma unroll
        for (int i = 0; i < 4; i++)
            af[i] = *(const short8*)&As[(wm + i * 16 + lr) * 32 + lq * 8];
        #pragma unroll
        for (int j = 0; j < 4; j++)
            bfr[j] = *(const short8*)&Bs[(wn + j * 16 + lr) * 32 + lq * 8];
        #pragma unroll
        for (int i = 0; i < 4; i++)
            #pragma unroll
            for (int j = 0; j < 4; j++)
                acc[i][j] = __builtin_amdgcn_mfma_f32_16x16x32_bf16(
                    af[i], bfr[j], acc[i][j], 0, 0, 0);
        __syncthreads();
    }

    #pragma unroll
    for (int j = 0; j < 4; j++) {
        int col = c0 + wn + j * 16 + lr;
        if (col >= NREAL) continue;
        int seg = col / 300, jj = col - seg * 300;
        float b = bcat[col];
        #pragma unroll
        for (int i = 0; i < 4; i++) {
            #pragma unroll
            for (int rg = 0; rg < 4; rg++) {
                int row = r0 + wm + i * 16 + lq * 4 + rg;
                if (row >= M) continue;
                float v = acc[i][j][rg] + b;
                size_t idx = (size_t)row * 300 + jj;
                switch (seg) {
                    case 0: Q [idx] = __float2bfloat16(v); break;
                    case 1: Kf[idx] = __float2bfloat16(v); break;
                    case 2: V [idx] = __float2bfloat16(v); break;
                    case 3: Ot[idx] = v;                   break;
                    case 4: Pi[idx] = __float2bfloat16(v); break;
                    default: Pj[idx] = __float2bfloat16(v); break;
                }
            }
        }
    }
}

// ---------------- QE8 precompute: QE8[n][h][t] = dot(Q[n] head h, E8[t] head h) ----------------
__global__ __launch_bounds__(256) void qe8_pre(
    const bf16* __restrict__ Q, const float* __restrict__ E8,
    float* __restrict__ QE8, int N)
{
    const int wid  = threadIdx.x >> 6;
    const int lane = threadIdx.x & 63;
    const int n = blockIdx.x * 4 + wid;
    if (n >= N) return;
    const size_t qrow = (size_t)n * 300;
    #pragma unroll
    for (int h = 0; h < 4; h++) {
        float a[8];
        #pragma unroll
        for (int t = 0; t < 8; t++) a[t] = 0.f;
        #pragma unroll
        for (int part = 0; part < 2; part++) {
            int off = part * 64 + lane;
            bool val = off < 75;
            int c = h * 75 + (val ? off : 0);
            float qv = val ? __bfloat162float(Q[qrow + c]) : 0.f;
            #pragma unroll
            for (int t = 0; t < 8; t++) a[t] += qv * E8[t * 300 + c];
        }
        #pragma unroll
        for (int t = 0; t < 8; t++) {
            #pragma unroll
            for (int m = 1; m < 64; m <<= 1) a[t] += __shfl_xor(a[t], m, 64);
        }
        if (lane == 0) {
            #pragma unroll
            for (int t = 0; t < 8; t++) QE8[(size_t)n * 32 + h * 8 + t] = a[t];
        }
    }
}

// ---------------- per-edge phase 1: tanh/softmax/alpha ----------------
__global__ __launch_bounds__(256) void edge_phase1(
    const int* __restrict__ ei, const float* __restrict__ ea,
    const bf16* __restrict__ Q, const bf16* __restrict__ Kf,
    const bf16* __restrict__ Pi, const bf16* __restrict__ Pj,
    const float* __restrict__ Mxy, const float* __restrict__ bgeo,
    const float* __restrict__ E8, const float* __restrict__ QE8,
    const float* __restrict__ Wcls, const float* __restrict__ bcls,
    bf16* __restrict__ coef, float* __restrict__ aexp, float* __restrict__ den,
    int E, int adv)
{
    const int wid  = threadIdx.x >> 6;
    const int lane = threadIdx.x & 63;
    const int e = blockIdx.x * 4 + wid;
    if (e >= E) return;
    const int s = ei[e];
    const int d = ei[E + e];
    const float ea0 = ea[(size_t)e*4+0], ea1 = ea[(size_t)e*4+1];
    const float ea2 = ea[(size_t)e*4+2], ea3 = ea[(size_t)e*4+3];
    const size_t drow = (size_t)d * 300, srow = (size_t)s * 300;

    float tt[5];
    #pragma unroll
    for (int r = 0; r < 5; r++) {
        int c = lane + 64 * r;
        float v = 0.f;
        if (c < 300) {
            v = __bfloat162float(Pi[drow + c]) + __bfloat162float(Pj[srow + c])
              + ea2 * Mxy[c] + ea3 * Mxy[300 + c] + bgeo[c];
            v = fminf(fmaxf(v, -15.f), 15.f);
            float ex = __expf(2.f * v);
            v = (ex - 1.f) / (ex + 1.f);          // tanh
        }
        tt[r] = v;
    }
    float lg[5];
    #pragma unroll
    for (int cl = 0; cl < 5; cl++) {
        float p = 0.f;
        #pragma unroll
        for (int r = 0; r < 5; r++) {
            int c = lane + 64 * r;
            if (c < 300) p += tt[r] * Wcls[c * 5 + cl];
        }
        #pragma unroll
        for (int m = 1; m < 64; m <<= 1) p += __shfl_xor(p, m, 64);
        lg[cl] = p + bcls[cl];
    }
    float mx = lg[0];
    #pragma unroll
    for (int cl = 1; cl < 5; cl++) mx = fmaxf(mx, lg[cl]);
    float pr[5], psum = 0.f;
    #pragma unroll
    for (int cl = 0; cl < 5; cl++) { pr[cl] = __expf(lg[cl] - mx); psum += pr[cl]; }
    const float pinv = 1.f / psum;
    #pragma unroll
    for (int cl = 0; cl < 5; cl++) pr[cl] *= pinv;

    const float ctop = ea0 > 0.f ? 1.f : 0.f;
    const float cbot = ea1 < 0.f ? 1.f : 0.f;
    if (lane < 8) {
        float cv;
        switch (lane) {
            case 0: cv = ctop;  break; case 1: cv = cbot;  break;
            case 2: cv = pr[0]; break; case 3: cv = pr[1]; break;
            case 4: cv = pr[2]; break; case 5: cv = pr[3]; break;
            case 6: cv = pr[4]; break; default: cv = 1.f;  break;
        }
        coef[(size_t)e * 8 + lane] = __float2bfloat16(cv);
    }
    // alpha = q.k (+ q.ef via QE8 in adv path, inline in fallback)
    float h0 = 0.f, h1 = 0.f, h2 = 0.f, h3 = 0.f;
    if (adv) {
        #pragma unroll
        for (int r = 0; r < 5; r++) {
            int c = lane + 64 * r;
            if (c < 300) {
                float p = __bfloat162float(Q[drow + c]) * __bfloat162float(Kf[srow + c]);
                if (r == 0) h0 += p;
                else if (r == 1) { if (c < 75)  h0 += p; else h1 += p; }
                else if (r == 2) { if (c < 150) h1 += p; else h2 += p; }
                else if (r == 3) { if (c < 225) h2 += p; else h3 += p; }
                else h3 += p;
            }
        }
    } else {
        #pragma unroll
        for (int r = 0; r < 5; r++) {
            int c = lane + 64 * r;
            if (c < 300) {
                float efv = ctop * E8[c] + cbot * E8[300 + c]
                          + pr[0] * E8[600 + c] + pr[1] * E8[900 + c] + pr[2] * E8[1200 + c]
                          + pr[3] * E8[1500 + c] + pr[4] * E8[1800 + c] + E8[2100 + c];
                float p = __bfloat162float(Q[drow + c])
                        * (__bfloat162float(Kf[srow + c]) + efv);
                if (r == 0) h0 += p;
                else if (r == 1) { if (c < 75)  h0 += p; else h1 += p; }
                else if (r == 2) { if (c < 150) h1 += p; else h2 += p; }
                else if (r == 3) { if (c < 225) h2 += p; else h3 += p; }
                else h3 += p;
            }
        }
    }
    #pragma unroll
    for (int m = 1; m < 64; m <<= 1) {
        h0 += __shfl_xor(h0, m, 64);
        h1 += __shfl_xor(h1, m, 64);
        h2 += __shfl_xor(h2, m, 64);
        h3 += __shfl_xor(h3, m, 64);
    }
    const float isc = 0.11547005383792516f;   // 1/sqrt(75)
    if (lane < 4) {
        float av = (lane == 0) ? h0 : (lane == 1) ? h1 : (lane == 2) ? h2 : h3;
        if (adv) {
            float cf[8] = {ctop, cbot, pr[0], pr[1], pr[2], pr[3], pr[4], 1.f};
            const float* qq = QE8 + (size_t)d * 32 + lane * 8;
            float qe = 0.f;
            #pragma unroll
            for (int t = 0; t < 8; t++) qe += cf[t] * qq[t];
            av += qe;
        }
        av = __expf(av * isc);
        aexp[(size_t)e * 4 + lane] = av;
        atomicAdd(&den[(size_t)d * 4 + lane], av);
    }
}

// ---------------- per-edge phase 2: weighted scatter ----------------
__global__ __launch_bounds__(256) void edge_phase2(
    const int* __restrict__ ei,
    const bf16* __restrict__ Vf, const float* __restrict__ E8,
    const bf16* __restrict__ coef, const float* __restrict__ aexp,
    const float* __restrict__ den, float* __restrict__ S,
    float* __restrict__ Ot, int E, int adv)
{
    const int wid  = threadIdx.x >> 6;
    const int lane = threadIdx.x & 63;
    const int e = blockIdx.x * 4 + wid;
    if (e >= E) return;
    const int s = ei[e];
    const int d = ei[E + e];
    const float w0 = aexp[(size_t)e*4+0] / den[(size_t)d*4+0];
    const float w1 = aexp[(size_t)e*4+1] / den[(size_t)d*4+1];
    const float w2 = aexp[(size_t)e*4+2] / den[(size_t)d*4+2];
    const float w3 = aexp[(size_t)e*4+3] / den[(size_t)d*4+3];
    const size_t drow = (size_t)d * 300, srow = (size_t)s * 300;

    if (adv) {
        // S[d][h][t] += w_h * coef_t  (ef contribution factored out; finalize applies S.E8)
        if (lane < 32) {
            int h = lane >> 3, t = lane & 7;
            float wv = (h == 0) ? w0 : (h == 1) ? w1 : (h == 2) ? w2 : w3;
            float cv = __bfloat162float(coef[(size_t)e * 8 + t]);
            atomicAdd(&S[(size_t)d * 32 + lane], wv * cv);
        }
        #pragma unroll
        for (int r = 0; r < 5; r++) {
            int c = lane + 64 * r;
            if (c < 300) {
                float w = (r == 0) ? w0
                        : (r == 1) ? (c < 75  ? w0 : w1)
                        : (r == 2) ? (c < 150 ? w1 : w2)
                        : (r == 3) ? (c < 225 ? w2 : w3)
                        : w3;
                atomicAdd(&Ot[drow + c], __bfloat162float(Vf[srow + c]) * w);
            }
        }
    } else {
        const float c0 = __bfloat162float(coef[(size_t)e*8+0]);
        const float c1 = __bfloat162float(coef[(size_t)e*8+1]);
        const float c2 = __bfloat162float(coef[(size_t)e*8+2]);
        const float c3 = __bfloat162float(coef[(size_t)e*8+3]);
        const float c4 = __bfloat162float(coef[(size_t)e*8+4]);
        const float c5 = __bfloat162float(coef[(size_t)e*8+5]);
        const float c6 = __bfloat162float(coef[(size_t)e*8+6]);
        #pragma unroll
        for (int r = 0; r < 5; r++) {
            int c = lane + 64 * r;
            if (c < 300) {
                float efv = c0 * E8[c] + c1 * E8[300 + c] + c2 * E8[600 + c] + c3 * E8[900 + c]
                          + c4 * E8[1200 + c] + c5 * E8[1500 + c] + c6 * E8[1800 + c] + E8[2100 + c];
                float w = (r == 0) ? w0
                        : (r == 1) ? (c < 75  ? w0 : w1)
                        : (r == 2) ? (c < 150 ? w1 : w2)
                        : (r == 3) ? (c < 225 ? w2 : w3)
                        : w3;
                atomicAdd(&Ot[drow + c], (__bfloat162float(Vf[srow + c]) + efv) * w);
            }
        }
    }
}

// ---------------- finalize: out[n] += S[n] . E8 (adv path only) ----------------
__global__ __launch_bounds__(256) void finalize_s(
    float* __restrict__ Ot, const float* __restrict__ S,
    const float* __restrict__ E8, int N)
{
    const int wid  = threadIdx.x >> 6;
    const int lane = threadIdx.x & 63;
    const int n = blockIdx.x * 4 + wid;
    if (n >= N) return;
    #pragma unroll
    for (int r = 0; r < 5; r++) {
        int c = lane + 64 * r;
        if (c < 300) {
            int h = c / 75;
            const float* sp = S + (size_t)n * 32 + h * 8;
            float a = 0.f;
            #pragma unroll
            for (int t = 0; t < 8; t++) a += sp[t] * E8[t * 300 + c];
            Ot[(size_t)n * 300 + c] += a;
        }
    }
}

// ---------------- launch ----------------
extern "C" void kernel_launch(void* const* d_in, const int* in_sizes, int n_in,
                              void* d_out, int out_size, void* d_ws, size_t ws_size,
                              hipStream_t stream)
{
    const float* x     = (const float*)d_in[0];
    const int*   ei    = (const int*)  d_in[1];
    const float* ea    = (const float*)d_in[2];
    const float* on    = (const float*)d_in[3];
    const float* Wq    = (const float*)d_in[4];
    const float* bq    = (const float*)d_in[5];
    const float* Wk    = (const float*)d_in[6];
    const float* bk    = (const float*)d_in[7];
    const float* Wv    = (const float*)d_in[8];
    const float* bv    = (const float*)d_in[9];
    const float* We    = (const float*)d_in[10];
    const float* Wn    = (const float*)d_in[11];
    const float* bn    = (const float*)d_in[12];
    const float* Wxy   = (const float*)d_in[13];
    const float* bxy   = (const float*)d_in[14];
    const float* Wloc  = (const float*)d_in[15];
    const float* bloc  = (const float*)d_in[16];
    const float* Wobj  = (const float*)d_in[17];
    const float* bobj  = (const float*)d_in[18];
    const float* Wfus  = (const float*)d_in[19];
    const float* bfus  = (const float*)d_in[20];
    const float* Wcls  = (const float*)d_in[21];
    const float* bcls  = (const float*)d_in[22];
    const float* Wskip = (const float*)d_in[23];
    const float* bskip = (const float*)d_in[24];
    const float* vocab = (const float*)d_in[25];

    const int N = in_sizes[0] / NDIM;
    const int E = in_sizes[1] / 2;

    // ---- workspace layout: bf16 region, then fp32 region; adv extras at the end ----
    const size_t nodeElems = (size_t)N * 300;
    const size_t wcatElems = (size_t)NPAD * KPAD;
    const size_t bf16Elems = 5 * nodeElems + wcatElems + (size_t)E * 8;  // + coef bf16
    size_t f32Base = NREAL                                    // bcat
                   + (size_t)E * 4                            // aexp
                   + (size_t)N * 4                            // den
                   + 904 + 904 + 600 + 304 + 1504 + 304 + 304 + 2400;
    size_t need_base = bf16Elems * sizeof(bf16) + f32Base * sizeof(float);
    size_t need_adv  = need_base + 2 * (size_t)N * 32 * sizeof(float);   // QE8 + S
    if (ws_size < need_base) return;
    const int adv = (ws_size >= need_adv) ? 1 : 0;

    bf16* wsh = (bf16*)d_ws;
    bf16* Qb    = wsh;                 bf16* Kb  = Qb + nodeElems;
    bf16* Vb    = Kb + nodeElems;      bf16* Pib = Vb + nodeElems;
    bf16* Pjb   = Pib + nodeElems;
    bf16* WcatT = Pjb + nodeElems;
    bf16* coefb = WcatT + wcatElems;
    float* ws = (float*)(coefb + (size_t)E * 8);
    size_t o = 0;
    float* bcat  = ws + o; o += NREAL;
    float* aexpb = ws + o; o += (size_t)E * 4;
    float* denb  = ws + o; o += (size_t)N * 4;
    float* Wn1   = ws + o; o += 904;
    float* Wn2   = ws + o; o += 904;
    float* Mxyb  = ws + o; o += 600;
    float* bgeo  = ws + o; o += 304;
    float* vf5   = ws + o; o += 1504;
    float* t0b   = ws + o; o += 304;
    float* t1b   = ws + o; o += 304;
    float* E8b   = ws + o; o += 2400;
    float* QE8b  = ws + o; o += (size_t)N * 32;   // valid only if adv
    float* Sb    = ws + o; o += (size_t)N * 32;   // valid only if adv
    (void)n_in; (void)out_size;

    hipMemsetAsync(denb, 0, (size_t)N * 4 * sizeof(float), stream);
    if (adv) hipMemsetAsync(Sb, 0, (size_t)N * 32 * sizeof(float), stream);

    small_pre<<<19, 256, 0, stream>>>(Wn, bn, Wxy, bxy, Wloc, bloc, bobj, Wfus, vocab,
                                      Wn1, Wn2, Mxyb, bgeo, vf5, t0b, t1b);
    small_pre2<<<10, 256, 0, stream>>>(We, bfus, vf5, t0b, t1b, E8b);
    pack_w<<<(NPAD * KPAD + 255) / 256, 256, 0, stream>>>(
        Wq, Wk, Wv, Wskip, Wobj, Wn1, Wn2, bq, bk, bv, bskip, WcatT, bcat);

    dim3 g1(NPAD / 128, (N + 127) / 128);
    gemm_mfma<<<g1, 256, 0, stream>>>(x, on, WcatT, bcat,
                                      Qb, Kb, Vb, (float*)d_out, Pib, Pjb, N);

    const int nb = (N + 3) / 4;
    if (adv) qe8_pre<<<nb, 256, 0, stream>>>(Qb, E8b, QE8b, N);

    const int eb = (E + 3) / 4;
    edge_phase1<<<eb, 256, 0, stream>>>(ei, ea, Qb, Kb, Pib, Pjb, Mxyb, bgeo, E8b, QE8b,
                                        Wcls, bcls, coefb, aexpb, denb, E, adv);
    edge_phase2<<<eb, 256, 0, stream>>>(ei, Vb, E8b, coefb, aexpb, denb, Sb,
                                        (float*)d_out, E, adv);
    if (adv) finalize_s<<<nb, 256, 0, stream>>>((float*)d_out, Sb, E8b, N);
}

// Round 5
// 1113.357 us; speedup vs baseline: 1.1890x; 1.1890x over previous
//
#include <hip/hip_runtime.h>
#include <hip/hip_bf16.h>
#include <math.h>

#define NDIM 300
#define KPAD 320          // K padded: 300 x-dims + 3 normal dims + zeros
#define NREAL 1800
#define NPAD 1920         // 15 tiles of 128

typedef __hip_bfloat16 bf16;
typedef __attribute__((ext_vector_type(8))) short short8;   // 8 bf16 (4 VGPRs)
typedef __attribute__((ext_vector_type(4))) float f32x4;

__device__ __forceinline__ void gl_lds16(const void* g, void* l) {
    __builtin_amdgcn_global_load_lds(
        (const __attribute__((address_space(1))) void*)g,
        (__attribute__((address_space(3))) void*)l, 16, 0, 0);
}

__device__ __forceinline__ float wredsum(float v) {
    #pragma unroll
    for (int m = 1; m < 64; m <<= 1) v += __shfl_xor(v, m, 64);
    return v;
}

// ---------------- tiny constant-folding kernels ----------------
__global__ void small_pre(
    const float* __restrict__ Wn, const float* __restrict__ bn,
    const float* __restrict__ Wxy, const float* __restrict__ bxy,
    const float* __restrict__ Wloc, const float* __restrict__ bloc,
    const float* __restrict__ bobj,
    const float* __restrict__ Wfus,
    const float* __restrict__ vocab,
    float* __restrict__ Wn1, float* __restrict__ Wn2,
    float* __restrict__ Mxy, float* __restrict__ bgeo,
    float* __restrict__ vf5, float* __restrict__ t0, float* __restrict__ t1)
{
    int i = blockIdx.x * blockDim.x + threadIdx.x;
    if (i < 900) {
        int r = i / 300, c = i % 300;
        float s = 0.f;
        for (int k = 0; k < 300; k++) s += Wn[r*300+k] * Wloc[(300+k)*300+c];
        Wn1[i] = s;
    } else if (i < 1800) {
        int j = i - 900; int r = j/300, c = j%300;
        float s = 0.f;
        for (int k = 0; k < 300; k++) s += Wn[r*300+k] * Wloc[(600+k)*300+c];
        Wn2[j] = s;
    } else if (i < 2400) {
        int j = i - 1800; int r = j/300, c = j%300;
        float s = 0.f;
        for (int k = 0; k < 300; k++) s += Wxy[r*300+k] * Wloc[k*300+c];
        Mxy[j] = s;
    } else if (i < 2700) {
        int c = i - 2400;
        float s = bloc[c] + bobj[c];
        for (int k = 0; k < 300; k++) s += bxy[k] * Wloc[k*300+c];
        for (int k = 0; k < 300; k++) s += bn[k] * (Wloc[(300+k)*300+c] + Wloc[(600+k)*300+c]);
        bgeo[c] = s;
    } else if (i < 4200) {
        int j = i - 2700; int p = j/300, c = j%300;
        float s = 0.f;
        for (int k = 0; k < 300; k++) s += vocab[(2+p)*300+k] * Wfus[(300+k)*300+c];
        vf5[j] = s;
    } else if (i < 4500) {
        int c = i - 4200;
        float s = 0.f;
        for (int k = 0; k < 300; k++) s += vocab[k] * Wfus[k*300+c];
        t0[c] = s;
    } else if (i < 4800) {
        int c = i - 4500;
        float s = 0.f;
        for (int k = 0; k < 300; k++) s += vocab[300+k] * Wfus[k*300+c];
        t1[c] = s;
    }
}

__global__ void small_pre2(
    const float* __restrict__ We, const float* __restrict__ bfus,
    const float* __restrict__ vf5, const float* __restrict__ t0, const float* __restrict__ t1,
    const float* __restrict__ Wcls,
    float* __restrict__ E8, float* __restrict__ WclsT)
{
    int i = blockIdx.x * blockDim.x + threadIdx.x;
    if (i < 2400) {
        int r = i / 300, c = i % 300;
        const float* src;
        if (r == 0) src = t0;
        else if (r == 1) src = t1;
        else if (r == 7) src = bfus;
        else src = vf5 + (r - 2) * 300;
        float s = 0.f;
        for (int k = 0; k < 300; k++) s += src[k] * We[k*300+c];
        E8[i] = s;
    } else if (i < 3900) {
        int j = i - 2400; int cl = j / 300, c = j % 300;
        WclsT[cl * 300 + c] = Wcls[c * 5 + cl];
    }
}

// pack weights into WcatT[NPAD][KPAD] bf16 (transposed, K contiguous) + bcat fp32
__global__ void pack_w(
    const float* __restrict__ Wq, const float* __restrict__ Wk,
    const float* __restrict__ Wv, const float* __restrict__ Wskip,
    const float* __restrict__ Wobj,
    const float* __restrict__ Wn1, const float* __restrict__ Wn2,
    const float* __restrict__ bq, const float* __restrict__ bk,
    const float* __restrict__ bv, const float* __restrict__ bskip,
    bf16* __restrict__ WcatT, float* __restrict__ bcat)
{
    int i = blockIdx.x * blockDim.x + threadIdx.x;
    if (i < NREAL) {
        int seg = i / 300, jj = i % 300;
        float b = 0.f;
        if (seg == 0) b = bq[jj]; else if (seg == 1) b = bk[jj];
        else if (seg == 2) b = bv[jj]; else if (seg == 3) b = bskip[jj];
        bcat[i] = b;
    }
    if (i < NPAD * KPAD) {
        int c = i / KPAD, k = i % KPAD;
        float v = 0.f;
        if (c < NREAL) {
            int seg = c / 300, jj = c % 300;
            if (k < 300) {
                switch (seg) {
                    case 0: v = Wq[k*300+jj]; break;
                    case 1: v = Wk[k*300+jj]; break;
                    case 2: v = Wv[k*300+jj]; break;
                    case 3: v = Wskip[k*300+jj]; break;
                    case 4: v = Wobj[k*300+jj] - Wobj[(300+k)*300+jj]; break;
                    default: v = Wobj[(300+k)*300+jj]; break;
                }
            } else if (k < 303) {
                if (seg == 4) v = Wn1[(k-300)*300+jj];
                else if (seg == 5) v = Wn2[(k-300)*300+jj];
            }
        }
        WcatT[i] = __float2bfloat16(v);
    }
}

// ---------------- counting sort of edges by dst ----------------
__global__ void hist_k(const int* __restrict__ ei, int* __restrict__ deg, int E) {
    int e = blockIdx.x * blockDim.x + threadIdx.x;
    if (e < E) atomicAdd(&deg[ei[E + e]], 1);
}

__global__ __launch_bounds__(1024) void scan_k(
    const int* __restrict__ deg, int* __restrict__ off, int* __restrict__ cur, int N)
{
    __shared__ int buf[1024];
    __shared__ int carry;
    const int tid = threadIdx.x;
    if (tid == 0) carry = 0;
    __syncthreads();
    for (int base = 0; base < N; base += 1024) {
        int i = base + tid;
        int v = (i < N) ? deg[i] : 0;
        buf[tid] = v;
        __syncthreads();
        #pragma unroll
        for (int ofs = 1; ofs < 1024; ofs <<= 1) {
            int t = (tid >= ofs) ? buf[tid - ofs] : 0;
            __syncthreads();
            buf[tid] += t;
            __syncthreads();
        }
        int incl = buf[tid];
        int cbase = carry;
        if (i < N) { off[i] = cbase + incl - v; cur[i] = cbase + incl - v; }
        __syncthreads();
        if (tid == 0) carry = cbase + buf[1023];
        __syncthreads();
    }
    if (tid == 0) off[N] = carry;
}

__global__ void scatter_k(const int* __restrict__ ei, int* __restrict__ cur,
                          int* __restrict__ eorder, int E) {
    int e = blockIdx.x * blockDim.x + threadIdx.x;
    if (e < E) {
        int d = ei[E + e];
        int p = atomicAdd(&cur[d], 1);
        eorder[p] = e;
    }
}

// ---------------- MFMA node-GEMM: [N,320]bf16 @ [320,1920]bf16, double-buffered ----------------
__global__ __launch_bounds__(256) void gemm_mfma(
    const float* __restrict__ X, const float* __restrict__ Nrm,
    const bf16* __restrict__ Bt, const float* __restrict__ bcat,
    bf16* __restrict__ Q, bf16* __restrict__ Kf, bf16* __restrict__ V,
    float* __restrict__ Ot, bf16* __restrict__ Pi, bf16* __restrict__ Pj,
    int M)
{
    __shared__ __align__(16) bf16 As[2][128 * 32];
    __shared__ __align__(16) bf16 Bs[2][128 * 32];

    const int tid  = threadIdx.x;
    const int wave = tid >> 6;
    const int lane = tid & 63;
    const int r0 = blockIdx.y * 128;
    const int c0 = blockIdx.x * 128;
    const int wm = (wave >> 1) * 64;
    const int wn = (wave & 1) * 64;
    const int lr = lane & 15;
    const int lq = lane >> 4;

    f32x4 acc[4][4];   // acc[j][i]: j = W-col subtile (MFMA M), i = X-row subtile (MFMA N)
    #pragma unroll
    for (int j = 0; j < 4; j++)
        #pragma unroll
        for (int i = 0; i < 4; i++) acc[j][i] = (f32x4){0.f, 0.f, 0.f, 0.f};

    const int arow_l = tid >> 1;
    const int akp    = (tid & 1) * 16;
    const int agrow  = min(r0 + arow_l, M - 1);
    const float* xr = X + (size_t)agrow * 300;
    const float* nr = Nrm + (size_t)agrow * 3;
    const int bcol_l = lane >> 2;
    const int bkp    = (lane & 3) * 8;

    auto stage = [&](int buf, int kb) {
        // A: fp32 -> bf16 through regs, ds_write
        int g = kb + akp;
        union { bf16 h[16]; short8 s[2]; } u;
        if (g + 16 <= 300) {
            const float4 f0 = *(const float4*)(xr + g);
            const float4 f1 = *(const float4*)(xr + g + 4);
            const float4 f2 = *(const float4*)(xr + g + 8);
            const float4 f3 = *(const float4*)(xr + g + 12);
            u.h[0]=__float2bfloat16(f0.x); u.h[1]=__float2bfloat16(f0.y);
            u.h[2]=__float2bfloat16(f0.z); u.h[3]=__float2bfloat16(f0.w);
            u.h[4]=__float2bfloat16(f1.x); u.h[5]=__float2bfloat16(f1.y);
            u.h[6]=__float2bfloat16(f1.z); u.h[7]=__float2bfloat16(f1.w);
            u.h[8]=__float2bfloat16(f2.x); u.h[9]=__float2bfloat16(f2.y);
            u.h[10]=__float2bfloat16(f2.z); u.h[11]=__float2bfloat16(f2.w);
            u.h[12]=__float2bfloat16(f3.x); u.h[13]=__float2bfloat16(f3.y);
            u.h[14]=__float2bfloat16(f3.z); u.h[15]=__float2bfloat16(f3.w);
        } else {
            #pragma unroll
            for (int t = 0; t < 16; t++) {
                int gg = g + t;
                float v = 0.f;
                if (gg < 300)      v = xr[gg];
                else if (gg < 303) v = nr[gg - 300];
                u.h[t] = __float2bfloat16(v);
            }
        }
        *(short8*)&As[buf][arow_l * 32 + akp]     = u.s[0];
        *(short8*)&As[buf][arow_l * 32 + akp + 8] = u.s[1];
        // B: async 16B direct-to-LDS (dest = wave-uniform base + lane*16)
        #pragma unroll
        for (int h = 0; h < 2; h++) {
            int cloc = wave * 32 + h * 16;
            gl_lds16(Bt + (size_t)(c0 + cloc + bcol_l) * KPAD + kb + bkp,
                     &Bs[buf][cloc * 32]);
        }
    };

    stage(0, 0);
    #pragma unroll
    for (int it = 0; it < 10; it++) {
        __syncthreads();                       // drain staging of buf it&1
        if (it < 9) stage((it + 1) & 1, (it + 1) * 32);   // prefetch overlaps compute below
        const int b = it & 1;
        short8 af[4], bfr[4];
        #pragma unroll
        for (int i = 0; i < 4; i++)
            af[i] = *(const short8*)&As[b][(wm + i * 16 + lr) * 32 + lq * 8];
        #pragma unroll
        for (int j = 0; j < 4; j++)
            bfr[j] = *(const short8*)&Bs[b][(wn + j * 16 + lr) * 32 + lq * 8];
        #pragma unroll
        for (int j = 0; j < 4; j++)
            #pragma unroll
            for (int i = 0; i < 4; i++)
                acc[j][i] = __builtin_amdgcn_mfma_f32_16x16x32_bf16(
                    bfr[j], af[i], acc[j][i], 0, 0, 0);   // swapped: M=W-col, N=X-row
    }

    // epilogue: C/D with swapped operands -> X-row = lane&15, W-col = (lane>>4)*4 + reg
    // each lane's 4 regs = 4 consecutive output cols -> vector stores
    #pragma unroll
    for (int j = 0; j < 4; j++) {
        int colb = c0 + wn + j * 16 + lq * 4;
        if (colb >= NREAL) continue;           // 300 % 4 == 0: group never straddles segments
        int seg = colb / 300, jj = colb - seg * 300;
        float4 bb = *(const float4*)&bcat[colb];
        #pragma unroll
        for (int i = 0; i < 4; i++) {
            int row = r0 + wm + i * 16 + lr;
            if (row >= M) continue;
            float v0 = acc[j][i][0] + bb.x;
            float v1 = acc[j][i][1] + bb.y;
            float v2 = acc[j][i][2] + bb.z;
            float v3 = acc[j][i][3] + bb.w;
            size_t idx = (size_t)row * 300 + jj;
            if (seg == 3) {
                *(float4*)&Ot[idx] = make_float4(v0, v1, v2, v3);
            } else {
                union { bf16 h[4]; uint2 u2; } p;
                p.h[0] = __float2bfloat16(v0); p.h[1] = __float2bfloat16(v1);
                p.h[2] = __float2bfloat16(v2); p.h[3] = __float2bfloat16(v3);
                bf16* base = (seg == 0) ? Q : (seg == 1) ? Kf : (seg == 2) ? V
                           : (seg == 4) ? Pi : Pj;
                *(uint2*)&base[idx] = p.u2;
            }
        }
    }
}

// ---------------- fused edge pipeline: one wave per dst node, single pass ----------------
// out_d = skip_d + (sum_e aexp_e * (V_s + ef_e)) / den_d  -- deferred softmax normalization
__global__ __launch_bounds__(256) void edge_fused(
    const int* __restrict__ ei, const float* __restrict__ ea,
    const bf16* __restrict__ Q, const bf16* __restrict__ Kf,
    const bf16* __restrict__ V,
    const bf16* __restrict__ Pi, const bf16* __restrict__ Pj,
    const float* __restrict__ Mxy, const float* __restrict__ bgeo,
    const float* __restrict__ E8, const float* __restrict__ WclsT,
    const float* __restrict__ bcls,
    const int* __restrict__ off, const int* __restrict__ eorder,
    float* __restrict__ Ot, int N, int E)
{
    const int wid  = threadIdx.x >> 6;
    const int lane = threadIdx.x & 63;
    const int n = blockIdx.x * 4 + wid;
    if (n >= N) return;
    const int e0 = off[n], e1 = off[n + 1];
    if (e0 == e1) return;                       // out stays = skip
    const size_t nrow = (size_t)n * 300;

    float qv[5], piv[5], macc[5], mx0[5], mx1[5], bg[5];
    #pragma unroll
    for (int r = 0; r < 5; r++) {
        int c = lane + 64 * r;
        bool ok = c < 300;
        qv[r]  = ok ? __bfloat162float(Q[nrow + c])  : 0.f;
        piv[r] = ok ? __bfloat162float(Pi[nrow + c]) : 0.f;
        mx0[r] = ok ? Mxy[c]        : 0.f;
        mx1[r] = ok ? Mxy[300 + c]  : 0.f;
        bg[r]  = ok ? bgeo[c]       : 0.f;
        macc[r] = 0.f;
    }
    float bc[5];
    #pragma unroll
    for (int cl = 0; cl < 5; cl++) bc[cl] = bcls[cl];

    float den0 = 0.f, den1 = 0.f, den2 = 0.f, den3 = 0.f;
    const float isc = 0.11547005383792516f;     // 1/sqrt(75)

    for (int t = e0; t < e1; t++) {
        const int e = eorder[t];
        const int s = ei[e];
        const float ea0 = ea[(size_t)e*4+0], ea1 = ea[(size_t)e*4+1];
        const float ea2 = ea[(size_t)e*4+2], ea3 = ea[(size_t)e*4+3];
        const size_t srow = (size_t)s * 300;

        float pjv[5], kv[5], vv[5];
        #pragma unroll
        for (int r = 0; r < 5; r++) {
            int c = lane + 64 * r;
            bool ok = c < 300;
            pjv[r] = ok ? __bfloat162float(Pj[srow + c]) : 0.f;
            kv[r]  = ok ? __bfloat162float(Kf[srow + c]) : 0.f;
            vv[r]  = ok ? __bfloat162float(V [srow + c]) : 0.f;
        }
        float tt[5];
        #pragma unroll
        for (int r = 0; r < 5; r++) {
            float v = piv[r] + pjv[r] + ea2 * mx0[r] + ea3 * mx1[r] + bg[r];
            v = fminf(fmaxf(v, -15.f), 15.f);
            float ex = __expf(2.f * v);
            tt[r] = (ex - 1.f) / (ex + 1.f);    // tanh (==0 for padded lanes)
        }
        float lg[5];
        #pragma unroll
        for (int cl = 0; cl < 5; cl++) {
            float p = 0.f;
            #pragma unroll
            for (int r = 0; r < 5; r++) {
                int c = lane + 64 * r;
                if (c < 300) p += tt[r] * WclsT[cl * 300 + c];
            }
            lg[cl] = wredsum(p) + bc[cl];
        }
        float mxv = lg[0];
        #pragma unroll
        for (int cl = 1; cl < 5; cl++) mxv = fmaxf(mxv, lg[cl]);
        float pr[5], psum = 0.f;
        #pragma unroll
        for (int cl = 0; cl < 5; cl++) { pr[cl] = __expf(lg[cl] - mxv); psum += pr[cl]; }
        const float pinv = 1.f / psum;
        #pragma unroll
        for (int cl = 0; cl < 5; cl++) pr[cl] *= pinv;
        const float ctop = ea0 > 0.f ? 1.f : 0.f;
        const float cbot = ea1 < 0.f ? 1.f : 0.f;

        float efc[5];
        #pragma unroll
        for (int r = 0; r < 5; r++) {
            int c = lane + 64 * r;
            efc[r] = 0.f;
            if (c < 300) {
                efc[r] = ctop * E8[c] + cbot * E8[300 + c]
                       + pr[0] * E8[600 + c] + pr[1] * E8[900 + c] + pr[2] * E8[1200 + c]
                       + pr[3] * E8[1500 + c] + pr[4] * E8[1800 + c] + E8[2100 + c];
            }
        }
        // alpha per head
        float h0 = 0.f, h1 = 0.f, h2 = 0.f, h3 = 0.f;
        #pragma unroll
        for (int r = 0; r < 5; r++) {
            int c = lane + 64 * r;
            if (c < 300) {
                float p = qv[r] * (kv[r] + efc[r]);
                if (r == 0) h0 += p;
                else if (r == 1) { if (c < 75)  h0 += p; else h1 += p; }
                else if (r == 2) { if (c < 150) h1 += p; else h2 += p; }
                else if (r == 3) { if (c < 225) h2 += p; else h3 += p; }
                else h3 += p;
            }
        }
        h0 = wredsum(h0); h1 = wredsum(h1); h2 = wredsum(h2); h3 = wredsum(h3);
        const float ax0 = __expf(h0 * isc);
        const float ax1 = __expf(h1 * isc);
        const float ax2 = __expf(h2 * isc);
        const float ax3 = __expf(h3 * isc);
        den0 += ax0; den1 += ax1; den2 += ax2; den3 += ax3;

        #pragma unroll
        for (int r = 0; r < 5; r++) {
            int c = lane + 64 * r;
            float w = (r == 0) ? ax0
                    : (r == 1) ? (c < 75  ? ax0 : ax1)
                    : (r == 2) ? (c < 150 ? ax1 : ax2)
                    : (r == 3) ? (c < 225 ? ax2 : ax3)
                    : ax3;
            macc[r] += w * (vv[r] + efc[r]);
        }
    }

    const float rd0 = 1.f / den0, rd1 = 1.f / den1, rd2 = 1.f / den2, rd3 = 1.f / den3;
    #pragma unroll
    for (int r = 0; r < 5; r++) {
        int c = lane + 64 * r;
        if (c < 300) {
            float rd = (r == 0) ? rd0
                     : (r == 1) ? (c < 75  ? rd0 : rd1)
                     : (r == 2) ? (c < 150 ? rd1 : rd2)
                     : (r == 3) ? (c < 225 ? rd2 : rd3)
                     : rd3;
            Ot[nrow + c] += macc[r] * rd;
        }
    }
}

// ---------------- launch ----------------
extern "C" void kernel_launch(void* const* d_in, const int* in_sizes, int n_in,
                              void* d_out, int out_size, void* d_ws, size_t ws_size,
                              hipStream_t stream)
{
    const float* x     = (const float*)d_in[0];
    const int*   ei    = (const int*)  d_in[1];
    const float* ea    = (const float*)d_in[2];
    const float* on    = (const float*)d_in[3];
    const float* Wq    = (const float*)d_in[4];
    const float* bq    = (const float*)d_in[5];
    const float* Wk    = (const float*)d_in[6];
    const float* bk    = (const float*)d_in[7];
    const float* Wv    = (const float*)d_in[8];
    const float* bv    = (const float*)d_in[9];
    const float* We    = (const float*)d_in[10];
    const float* Wn    = (const float*)d_in[11];
    const float* bn    = (const float*)d_in[12];
    const float* Wxy   = (const float*)d_in[13];
    const float* bxy   = (const float*)d_in[14];
    const float* Wloc  = (const float*)d_in[15];
    const float* bloc  = (const float*)d_in[16];
    const float* Wobj  = (const float*)d_in[17];
    const float* bobj  = (const float*)d_in[18];
    const float* Wfus  = (const float*)d_in[19];
    const float* bfus  = (const float*)d_in[20];
    const float* Wcls  = (const float*)d_in[21];
    const float* bcls  = (const float*)d_in[22];
    const float* Wskip = (const float*)d_in[23];
    const float* bskip = (const float*)d_in[24];
    const float* vocab = (const float*)d_in[25];

    const int N = in_sizes[0] / NDIM;
    const int E = in_sizes[1] / 2;

    // ---- workspace layout: bf16 region, fp32 region, int region ----
    const size_t nodeElems = (size_t)N * 300;
    const size_t wcatElems = (size_t)NPAD * KPAD;
    const size_t bf16Elems = 5 * nodeElems + wcatElems;
    const size_t f32Elems  = NREAL + 904 + 904 + 600 + 304 + 1504 + 304 + 304 + 2400 + 1504;
    const size_t intElems  = (size_t)N + (size_t)(N + 1) + (size_t)N + (size_t)E;
    size_t need = bf16Elems * sizeof(bf16) + f32Elems * sizeof(float) + intElems * sizeof(int);
    if (ws_size < need) return;   // clean failure signal instead of OOB fault

    bf16* wsh = (bf16*)d_ws;
    bf16* Qb    = wsh;                 bf16* Kb  = Qb + nodeElems;
    bf16* Vb    = Kb + nodeElems;      bf16* Pib = Vb + nodeElems;
    bf16* Pjb   = Pib + nodeElems;
    bf16* WcatT = Pjb + nodeElems;
    float* ws = (float*)(WcatT + wcatElems);
    size_t o = 0;
    float* bcat  = ws + o; o += NREAL;
    float* Wn1   = ws + o; o += 904;
    float* Wn2   = ws + o; o += 904;
    float* Mxyb  = ws + o; o += 600;
    float* bgeo  = ws + o; o += 304;
    float* vf5   = ws + o; o += 1504;
    float* t0b   = ws + o; o += 304;
    float* t1b   = ws + o; o += 304;
    float* E8b   = ws + o; o += 2400;
    float* WclsT = ws + o; o += 1504;
    int* ip = (int*)(ws + o);
    int* deg    = ip;             ip += N;
    int* offb   = ip;             ip += N + 1;
    int* curb   = ip;             ip += N;
    int* eorder = ip;             ip += E;
    (void)n_in; (void)out_size;

    hipMemsetAsync(deg, 0, (size_t)N * sizeof(int), stream);

    small_pre<<<19, 256, 0, stream>>>(Wn, bn, Wxy, bxy, Wloc, bloc, bobj, Wfus, vocab,
                                      Wn1, Wn2, Mxyb, bgeo, vf5, t0b, t1b);
    small_pre2<<<16, 256, 0, stream>>>(We, bfus, vf5, t0b, t1b, Wcls, E8b, WclsT);
    pack_w<<<(NPAD * KPAD + 255) / 256, 256, 0, stream>>>(
        Wq, Wk, Wv, Wskip, Wobj, Wn1, Wn2, bq, bk, bv, bskip, WcatT, bcat);

    const int ebk = (E + 255) / 256;
    hist_k<<<ebk, 256, 0, stream>>>(ei, deg, E);
    scan_k<<<1, 1024, 0, stream>>>(deg, offb, curb, N);
    scatter_k<<<ebk, 256, 0, stream>>>(ei, curb, eorder, E);

    dim3 g1(NPAD / 128, (N + 127) / 128);
    gemm_mfma<<<g1, 256, 0, stream>>>(x, on, WcatT, bcat,
                                      Qb, Kb, Vb, (float*)d_out, Pib, Pjb, N);

    const int nb = (N + 3) / 4;
    edge_fused<<<nb, 256, 0, stream>>>(ei, ea, Qb, Kb, Vb, Pib, Pjb,
                                       Mxyb, bgeo, E8b, WclsT, bcls,
                                       offb, eorder, (float*)d_out, N, E);
}